// Round 1
// 105.198 us; speedup vs baseline: 1.2355x; 1.2355x over previous
//
#include <hip/hip_runtime.h>
#include <stdint.h>

typedef unsigned long long u64;

#define A_TOTAL 43008
#define NB 16
#define NM 128
#define SPLIT 168                 // blocks per batch; 4 waves; 64 anchors/lane-wave
#define WPB 4

// Bit-exact fp32 division via Markstein sequence: v_rcp + 2 Newton + residual
// correction, all full-rate fmas. Correctly rounded (== v_div result) for
// normal-range operands: here num in [0, ~1e5], den in [~64, ~4e5]; num==0
// yields exactly 0. Avoids the ~50-cycle div_scale/div_fmas/div_fixup chain.
__device__ __forceinline__ float exact_div(float x, float y) {
    float r;
    asm("v_rcp_f32 %0, %1" : "=v"(r) : "v"(y));
    float e  = __builtin_fmaf(-y, r, 1.0f);
    r        = __builtin_fmaf(e, r, r);
    e        = __builtin_fmaf(-y, r, 1.0f);
    r        = __builtin_fmaf(e, r, r);
    float q  = x * r;
    float rs = __builtin_fmaf(-y, q, x);
    return __builtin_fmaf(rs, r, q);
}

// u64 cross-lane DPP max-merge helper (pairs stay inside aligned 8-lane octets).
__device__ __forceinline__ u64 dpp_u64(u64 v, const int ctrl) {
    int lo = (int)(unsigned)v, hi = (int)(unsigned)(v >> 32);
    int plo, phi;
    switch (ctrl) {
        case 0xB1:   // quad_perm [1,0,3,2] : xor 1
            plo = __builtin_amdgcn_update_dpp(lo, lo, 0xB1, 0xF, 0xF, false);
            phi = __builtin_amdgcn_update_dpp(hi, hi, 0xB1, 0xF, 0xF, false);
            break;
        case 0x4E:   // quad_perm [2,3,0,1] : xor 2
            plo = __builtin_amdgcn_update_dpp(lo, lo, 0x4E, 0xF, 0xF, false);
            phi = __builtin_amdgcn_update_dpp(hi, hi, 0x4E, 0xF, 0xF, false);
            break;
        default:     // 0x141 row_half_mirror : p -> 7-p within octet
            plo = __builtin_amdgcn_update_dpp(lo, lo, 0x141, 0xF, 0xF, false);
            phi = __builtin_amdgcn_update_dpp(hi, hi, 0x141, 0xF, 0xF, false);
            break;
    }
    return ((u64)(unsigned)phi << 32) | (unsigned)plo;
}

// Tiny prep: bbox areas [NB*NM] + zero-init colfinal [NB*NM] + per-(batch,chunk)
// group bounds over 8-box chunks (for wave-uniform liveness skip). 8 blocks x 256.
__global__ __launch_bounds__(256) void prep_kernel(
    const float4* __restrict__ bboxes, float* __restrict__ areaBp,
    u64* __restrict__ colfinal, float4* __restrict__ chunkbnd) {
#pragma clang fp contract(off)
    const int i = blockIdx.x * 256 + threadIdx.x;    // 0..2047
    float4 v = bboxes[i];
    areaBp[i] = (v.z - v.x) * (v.w - v.y);
    colfinal[i] = 0ull;
    if (blockIdx.x == 0) {
        // thread t handles (b = t>>4, c = t&15): bounds over boxes c*8..c*8+7
        const int t = threadIdx.x;
        const int base = (t >> 4) * NM + (t & 15) * 8;
        float4 f = bboxes[base];
        float mnx = f.x, mny = f.y, mxx = f.z, mxy = f.w;
#pragma unroll
        for (int k = 1; k < 8; ++k) {
            float4 u = bboxes[base + k];
            mnx = fminf(mnx, u.x); mny = fminf(mny, u.y);
            mxx = fmaxf(mxx, u.z); mxy = fmaxf(mxy, u.w);
        }
        chunkbnd[t] = make_float4(mnx, mny, mxx, mxy);   // (min x1, min y1, max x2, max y2)
    }
}

// ---------------------------------------------------------------------------
// Fused IoU pass, lane = anchor / loop = box (R7 structure, exact_div inner),
// NOW with hierarchical wave-uniform zero-skip:
//   chunk level: lane-anchor vs 8-box group bounds, ballot==0 -> skip 8 boxes
//   box level:   lane-anchor vs box, ballot==0 -> skip compute+div+LDS write
// Skip is value-preserving: a lane failing the overlap test has inter==0 and
// iou==+0.0 bit-exactly, which can never win under strict '>' (row best init
// (0.0, m=0) == reference argmax of an all-zero row). Dead boxes keep col key
// 0 (s_ck pre-zeroed; stale s_col never read — col reduce gated by same mask).
// An all-zero colfinal column is impossible (512px level-2 anchors cover the
// whole image), and any wave holding a nonzero/tying iou is necessarily live,
// so the atomicMax tie-break set is unchanged.
// ---------------------------------------------------------------------------
__global__ __launch_bounds__(256) void fused_kernel(
    const float4* __restrict__ anchors, const float* __restrict__ bb,
    const float* __restrict__ areaBp, const float4* __restrict__ chunkbnd,
    u64* __restrict__ rowkey,        // [NB][A_TOTAL] (iou_bits<<32)|m
    u64* __restrict__ colfinal) {    // [NB][NM] atomicMax table
#pragma clang fp contract(off)
    const int b = blockIdx.y, tid = threadIdx.x;
    const int lane = tid & 63, wv = tid >> 6;
    const int abase = blockIdx.x * 256 + wv * 64;

    __shared__ float s_col[WPB][8][65];   // chunk transpose (2-way = free)
    __shared__ u64   s_ck[WPB][NM];       // per-wave col keys

    // pre-zero this wave's col keys (skipped chunks contribute 0)
    s_ck[wv][lane] = 0ull;
    s_ck[wv][64 + lane] = 0ull;

    // this lane's anchor, converted once (amortized over 128 box-iters)
    float4 an = anchors[abase + lane];
    float hw = an.z * 0.5f, hh = an.w * 0.5f;
    float ax1 = an.x - hw, ay1 = an.y - hh;
    float ax2 = an.x + hw, ay2 = an.y + hh;
    float areaA = (ax2 - ax1) * (ay2 - ay1);

    const float* box  = bb + (size_t)b * NM * 4;      // uniform -> s_load
    const float* area = areaBp + (size_t)b * NM;
    const float4* cb  = chunkbnd + (b << 4);

    float best_v = 0.0f; int best_m = 0;              // == ref argmax of zero row
    const int bi = lane >> 3, part = lane & 7;
    const int rbase = part * 8;

    for (int c = 0; c < 16; ++c) {
        // chunk-level liveness: this lane's anchor vs 8-box group bounds
        float4 g = cb[c];                              // uniform -> s_load
        bool cl = (g.z > ax1) & (g.x < ax2) & (g.w > ay1) & (g.y < ay2);
        if (__ballot(cl) == 0ull) continue;            // wave-uniform skip

        unsigned mask = 0;
#pragma unroll
        for (int i = 0; i < 8; ++i) {
            const int m = c * 8 + i;                   // wave-uniform
            const float bx1 = box[4 * m + 0], by1 = box[4 * m + 1];
            const float bx2 = box[4 * m + 2], by2 = box[4 * m + 3];
            bool lv = (bx2 > ax1) & (bx1 < ax2) & (by2 > ay1) & (by1 < ay2);
            if (__ballot(lv) != 0ull) {                // wave-uniform branch
                mask |= 1u << i;
                const float areaB = area[m];
                float ltx = fmaxf(ax1, bx1), lty = fmaxf(ay1, by1);
                float rbx = fminf(ax2, bx2), rby = fminf(ay2, by2);
                float wx = fmaxf(rbx - ltx, 0.0f), wy = fmaxf(rby - lty, 0.0f);
                float inter = wx * wy;
                float iou = exact_div(inter, (areaA + areaB) - inter);
                if (iou > best_v) { best_v = iou; best_m = m; }  // first m on tie
                s_col[wv][i][lane] = iou;
            }
        }
        if (mask == 0u) continue;                      // group bounds passed, all boxes dead

        // col chunk reduce: 8 lanes (parts) per box, 8 serial entries each;
        // octets of dead boxes contribute key 0 (never read stale s_col)
        u64 key = 0ull;
        if (mask & (1u << bi)) {
            float v = -1.0f; int tb = 0;
#pragma unroll
            for (int t = 0; t < 8; ++t) {             // ascending anchor
                float o = s_col[wv][bi][rbase + t];
                if (o > v) { v = o; tb = t; }         // strict > : smallest t
            }
            unsigned aidx = (unsigned)(abase + rbase + tb);
            key = ((u64)__float_as_uint(v) << 32) | (u64)(unsigned)(~aidx);
        }
        { u64 o = dpp_u64(key, 0xB1);  if (o > key) key = o; }
        { u64 o = dpp_u64(key, 0x4E);  if (o > key) key = o; }
        { u64 o = dpp_u64(key, 0x141); if (o > key) key = o; }
        if (part == 0) s_ck[wv][c * 8 + bi] = key;
    }

    rowkey[(size_t)b * A_TOTAL + abase + lane] =
        ((u64)__float_as_uint(best_v) << 32) | (u64)(unsigned)best_m;

    __syncthreads();
    if (tid < NM) {
        u64 k = s_ck[0][tid];
        for (int w = 1; w < WPB; ++w) if (s_ck[w][tid] > k) k = s_ck[w][tid];
        atomicMax(&colfinal[b * NM + tid], k);
    }
}

// Streaming epilogue (R5-proven): per-block override window + score + gather.
__global__ __launch_bounds__(256) void epilogue_kernel(
    const float4* __restrict__ bboxes, const int* __restrict__ labels,
    const u64* __restrict__ colfinal, const u64* __restrict__ rowkey,
    float* __restrict__ out_scores, float4* __restrict__ out_matched) {
#pragma clang fp contract(off)
    const int b = blockIdx.y, tid = threadIdx.x;
    const int a0 = blockIdx.x * 256, a = a0 + tid;   // A_TOTAL == 168*256

    __shared__ float4 sbox[NM];
    __shared__ float  s_cm[NM];
    __shared__ int    s_lab[NM];
    __shared__ int    ovr[256];
    ovr[tid] = -1;

    int my_ca = -1;
    if (tid < NM) {
        u64 k = colfinal[b * NM + tid];
        s_cm[tid] = __uint_as_float((unsigned)(k >> 32));
        my_ca = ~((int)(unsigned)(k & 0xFFFFFFFFull));   // recover anchor idx
        sbox[tid]  = bboxes[b * NM + tid];
        s_lab[tid] = labels[b * NM + tid];
    }
    __syncthreads();
    if (tid < NM && my_ca >= a0 && my_ca < a0 + 256)
        atomicMax(&ovr[my_ca - a0], tid);                // later j wins == max j
    __syncthreads();

    u64 rk = rowkey[(size_t)b * A_TOTAL + a];
    float best = __uint_as_float((unsigned)(rk >> 32));
    int   bi   = (int)(rk & 0xFFFFFFFFull);

    int o = ovr[tid];
    if (o >= 0) { bi = o; best = s_cm[o]; }

    float denom = fmaxf(s_cm[bi], 0.3f);        // IOU_THR
    float val   = (best < 0.15f) ? 0.0f : best; // IOU_THR * 0.5
    float score = val / denom;
    if (s_lab[bi] <= 0) score = 0.0f;

    out_scores[(size_t)b * A_TOTAL + a]  = score;
    out_matched[(size_t)b * A_TOTAL + a] = sbox[bi];
}

extern "C" void kernel_launch(void* const* d_in, const int* in_sizes, int n_in,
                              void* d_out, int out_size, void* d_ws, size_t ws_size,
                              hipStream_t stream) {
    const int*    labels  = (const int*)d_in[0];     // [NB, NM] int32
    const float4* bboxes  = (const float4*)d_in[1];  // [NB, NM, 4] xyxy
    const float4* anchors = (const float4*)d_in[2];  // [A_TOTAL, 4] cxcywh

    float* out = (float*)d_out;                      // scores [NB,A], matched [NB,A,4]

    char* ws = (char*)d_ws;
    u64*    rowkey   = (u64*)ws;                     ws += (size_t)NB * A_TOTAL * 8;
    u64*    colfinal = (u64*)ws;                     ws += (size_t)NB * NM * 8;
    float*  areaBp   = (float*)ws;                   ws += (size_t)NB * NM * 4;
    float4* chunkbnd = (float4*)ws;                  // [NB*16]

    prep_kernel<<<(NB * NM) / 256, 256, 0, stream>>>(bboxes, areaBp, colfinal,
                                                     chunkbnd);

    dim3 g(SPLIT, NB);
    fused_kernel<<<g, 256, 0, stream>>>(anchors, (const float*)bboxes, areaBp,
                                        chunkbnd, rowkey, colfinal);
    epilogue_kernel<<<g, 256, 0, stream>>>(
        bboxes, labels, colfinal, rowkey,
        out, (float4*)(out + (size_t)NB * A_TOTAL));
}